// Round 1
// baseline (755.572 us; speedup 1.0000x reference)
//
#include <hip/hip_runtime.h>
#include <cstdint>
#include <cmath>

#define SS 2048
#define HH 1024

typedef __bf16 bf16_t;
typedef __bf16 bf16x8 __attribute__((ext_vector_type(8)));
typedef __bf16 bf16x4 __attribute__((ext_vector_type(4)));
typedef float  f32x4  __attribute__((ext_vector_type(4)));

union U32P { unsigned u; bf16_t h[2]; };

__device__ __forceinline__ void async_load16(const void* g, void* l) {
  __builtin_amdgcn_global_load_lds(
      (__attribute__((address_space(1))) void*)(g),
      (__attribute__((address_space(3))) void*)(l), 16, 0, 0);
}

// ---------------- fp32 -> bf16 convert (grid covers exactly n/4 threads) ----
__global__ __launch_bounds__(256) void cvt_kernel(const float* __restrict__ in,
                                                  bf16_t* __restrict__ out) {
  size_t i = (size_t)blockIdx.x * 256 + threadIdx.x;
  f32x4 v = ((const f32x4*)in)[i];
  bf16x4 o;
  o[0] = (bf16_t)v[0]; o[1] = (bf16_t)v[1]; o[2] = (bf16_t)v[2]; o[3] = (bf16_t)v[3];
  ((bf16x4*)out)[i] = o;
}

// ---------------- LayerNorm: fp32 in [4096,1024] -> bf16 out ---------------
__global__ __launch_bounds__(256) void ln_kernel(const float* __restrict__ x,
                                                 const float* __restrict__ w,
                                                 const float* __restrict__ b,
                                                 bf16_t* __restrict__ out) {
  const int row = blockIdx.x;
  const int tid = threadIdx.x;
  const f32x4 v = ((const f32x4*)(x + (size_t)row * HH))[tid];
  float s  = v[0] + v[1] + v[2] + v[3];
  float s2 = v[0]*v[0] + v[1]*v[1] + v[2]*v[2] + v[3]*v[3];
#pragma unroll
  for (int o = 1; o < 64; o <<= 1) { s += __shfl_xor(s, o); s2 += __shfl_xor(s2, o); }
  __shared__ float r1[4], r2[4];
  if ((tid & 63) == 0) { r1[tid >> 6] = s; r2[tid >> 6] = s2; }
  __syncthreads();
  float ts  = r1[0] + r1[1] + r1[2] + r1[3];
  float ts2 = r2[0] + r2[1] + r2[2] + r2[3];
  float mu  = ts * (1.0f / HH);
  float var = ts2 * (1.0f / HH) - mu * mu;
  float rstd = rsqrtf(var + 1e-5f);
  f32x4 wv = ((const f32x4*)w)[tid];
  f32x4 bv = ((const f32x4*)b)[tid];
  bf16x4 o;
#pragma unroll
  for (int j = 0; j < 4; ++j) o[j] = (bf16_t)((v[j] - mu) * rstd * wv[j] + bv[j]);
  ((bf16x4*)(out + (size_t)row * HH))[tid] = o;
}

// ---------------- GEMM: C[M,N] = A[M,K] * W[N,K]^T + bias, fused epilogues --
// EPI: 0 = bias -> bf16 out; 1 = bias+gelu(exact) -> bf16 out; 2 = bias+residual -> f32 out
__device__ __forceinline__ float gelu_f(float x) {
  return 0.5f * x * (1.0f + erff(x * 0.70710678118654752f));
}

template <int EPI>
__global__ __launch_bounds__(256) void gemm_bt(const bf16_t* __restrict__ A,
                                               const bf16_t* __restrict__ W,
                                               const float* __restrict__ bias,
                                               const float* __restrict__ res,
                                               bf16_t* __restrict__ outb,
                                               float* __restrict__ outf,
                                               int M, int N, int K) {
  __shared__ __align__(16) bf16_t As[128 * 64];
  __shared__ __align__(16) bf16_t Bs[128 * 64];
  const int tid = threadIdx.x;
  const int w = tid >> 6, lane = tid & 63;
  const int m16 = lane & 15, quad = lane >> 4;
  const int wm = w & 1, wn = w >> 1;
  const int n0 = blockIdx.x * 128, m0 = blockIdx.y * 128;

  f32x4 acc[4][4];
#pragma unroll
  for (int i = 0; i < 4; ++i)
#pragma unroll
    for (int j = 0; j < 4; ++j) acc[i][j] = (f32x4){0.f, 0.f, 0.f, 0.f};

  // staging map: LDS 16B-chunk position p -> (row = p>>3, global col chunk = (p&7)^(row&7))
  int rowi[4], gci[4];
#pragma unroll
  for (int i = 0; i < 4; ++i) {
    int p = (w * 4 + i) * 64 + lane;
    rowi[i] = p >> 3;
    gci[i] = ((lane & 7) ^ (rowi[i] & 7)) * 8;
  }

  for (int kt = 0; kt < K; kt += 64) {
    __syncthreads();
#pragma unroll
    for (int i = 0; i < 4; ++i) {
      async_load16(A + (size_t)(m0 + rowi[i]) * K + kt + gci[i], &As[(w * 4 + i) * 512]);
      async_load16(W + (size_t)(n0 + rowi[i]) * K + kt + gci[i], &Bs[(w * 4 + i) * 512]);
    }
    __syncthreads();
#pragma unroll
    for (int kk = 0; kk < 2; ++kk) {
      bf16x8 af[4], bfv[4];
#pragma unroll
      for (int mi = 0; mi < 4; ++mi) {
        int row = wm * 64 + mi * 16 + m16;
        int cpos = (kk * 4 + quad) ^ (row & 7);
        af[mi] = *(const bf16x8*)&As[row * 64 + cpos * 8];
      }
#pragma unroll
      for (int ni = 0; ni < 4; ++ni) {
        int row = wn * 64 + ni * 16 + m16;
        int cpos = (kk * 4 + quad) ^ (row & 7);
        bfv[ni] = *(const bf16x8*)&Bs[row * 64 + cpos * 8];
      }
#pragma unroll
      for (int mi = 0; mi < 4; ++mi)
#pragma unroll
        for (int ni = 0; ni < 4; ++ni)
          acc[mi][ni] = __builtin_amdgcn_mfma_f32_16x16x32_bf16(af[mi], bfv[ni],
                                                                acc[mi][ni], 0, 0, 0);
    }
  }

#pragma unroll
  for (int ni = 0; ni < 4; ++ni) {
    int col = n0 + wn * 64 + ni * 16 + m16;
    float bv = bias[col];
#pragma unroll
    for (int mi = 0; mi < 4; ++mi) {
      int rowb = m0 + wm * 64 + mi * 16 + quad * 4;
#pragma unroll
      for (int r = 0; r < 4; ++r) {
        size_t idx = (size_t)(rowb + r) * N + col;
        float v = acc[mi][ni][r] + bv;
        if constexpr (EPI == 1) v = gelu_f(v);
        if constexpr (EPI == 2) outf[idx] = v + res[idx];
        else outb[idx] = (bf16_t)v;
      }
    }
  }
}

// ---------------- Flash attention (causal + ALiBi) -------------------------
// qkv: [B*S, 3072] bf16 (q|k|v sections, head-major h*64+d); ctx: [B*S,1024] bf16
// Transposed form: S^T = K*Q^T (both operands row-major-contiguous),
// O^T = V^T * P^T (P^T B-frag == P A-frag register layout; LDS round-trip).
__global__ __launch_bounds__(256) void attn_kernel(const bf16_t* __restrict__ qkv,
                                                   const float* __restrict__ alibi,
                                                   bf16_t* __restrict__ ctx) {
  const int qt = blockIdx.x;        // 64-row Q tile, 0..31
  const int bh = blockIdx.y;        // b*16 + h
  const int b = bh >> 4, h = bh & 15;
  const int tid = threadIdx.x;
  const int w = tid >> 6, lane = tid & 63;
  const int m16 = lane & 15, quad = lane >> 4;

  __shared__ __align__(16) bf16_t Kt[64 * 72];     // [key][d], pad 8
  __shared__ __align__(16) bf16_t Vt[64 * 72];     // [d][key], pad 8 (transposed)
  __shared__ __align__(16) bf16_t Pl[4][16 * 72];  // per-wave P[q][key], pad 8
  __shared__ float al[64];

  // Q B-fragments (n = q = lane&15, k = d = quad*8+j), loaded once
  const int qrow = qt * 64 + w * 16 + m16;
  const bf16_t* qbase = qkv + (size_t)(b * SS + qrow) * 3072 + h * 64;
  const bf16x8 bq0 = *(const bf16x8*)(qbase + quad * 8);
  const bf16x8 bq1 = *(const bf16x8*)(qbase + 32 + quad * 8);

  f32x4 acc[4];
#pragma unroll
  for (int i = 0; i < 4; ++i) acc[i] = (f32x4){0.f, 0.f, 0.f, 0.f};
  float m_run = -INFINITY, l_run = 0.f;

  const int kp = tid & 31, vd0 = (tid >> 5) * 8;  // V staging assignment
  const int ql = w * 16 + m16;                    // local q row (this lane's column)

  for (int kt = 0; kt <= qt; ++kt) {
    __syncthreads();
    const bf16_t* kvb = qkv + (size_t)(b * SS + kt * 64) * 3072 + h * 64;
#pragma unroll
    for (int i = 0; i < 2; ++i) {  // stage K row-major
      int c = tid + i * 256;
      int row = c >> 3, d0 = (c & 7) * 8;
      *(bf16x8*)&Kt[row * 72 + d0] = *(const bf16x8*)(kvb + 1024 + (size_t)row * 3072 + d0);
    }
    {  // stage V transposed: keys 2kp,2kp+1 x d0..d0+7 -> paired u32 writes
      bf16x8 v0 = *(const bf16x8*)(kvb + 2048 + (size_t)(2 * kp) * 3072 + vd0);
      bf16x8 v1 = *(const bf16x8*)(kvb + 2048 + (size_t)(2 * kp + 1) * 3072 + vd0);
#pragma unroll
      for (int j = 0; j < 8; ++j) {
        U32P pk; pk.h[0] = v0[j]; pk.h[1] = v1[j];
        *(unsigned*)&Vt[(vd0 + j) * 72 + 2 * kp] = pk.u;
      }
    }
    if (tid < 64) al[tid] = alibi[(size_t)bh * SS + kt * 64 + tid];
    __syncthreads();

    // S^T tile: D[key][q], 4 key-subtiles
    float p[4][4];
    float mx = -INFINITY;
    const bool diag = (kt == qt);
#pragma unroll
    for (int kn = 0; kn < 4; ++kn) {
      f32x4 z = (f32x4){0.f, 0.f, 0.f, 0.f};
      bf16x8 ak0 = *(const bf16x8*)&Kt[(kn * 16 + m16) * 72 + quad * 8];
      bf16x8 ak1 = *(const bf16x8*)&Kt[(kn * 16 + m16) * 72 + 32 + quad * 8];
      z = __builtin_amdgcn_mfma_f32_16x16x32_bf16(ak0, bq0, z, 0, 0, 0);
      z = __builtin_amdgcn_mfma_f32_16x16x32_bf16(ak1, bq1, z, 0, 0, 0);
#pragma unroll
      for (int r = 0; r < 4; ++r) {
        int kl = kn * 16 + quad * 4 + r;
        float s = z[r] * 0.125f + al[kl];   // alibi + qk/sqrt(64); layer_number cancels
        if (diag && kl > ql) s = -INFINITY; // causal
        p[kn][r] = s;
        mx = fmaxf(mx, s);
      }
    }
    mx = fmaxf(mx, __shfl_xor(mx, 16));
    mx = fmaxf(mx, __shfl_xor(mx, 32));
    float m_new = fmaxf(m_run, mx);
    float alpha = __expf(m_run - m_new);  // first tile: exp(-inf)=0
    float rs = 0.f;
#pragma unroll
    for (int kn = 0; kn < 4; ++kn)
#pragma unroll
      for (int r = 0; r < 4; ++r) { p[kn][r] = __expf(p[kn][r] - m_new); rs += p[kn][r]; }
    rs += __shfl_xor(rs, 16);
    rs += __shfl_xor(rs, 32);
    l_run = l_run * alpha + rs;
    m_run = m_new;
#pragma unroll
    for (int ni = 0; ni < 4; ++ni) acc[ni] *= alpha;

    // write P^T (this lane: q=m16, keys kn*16+quad*4+r) as paired u32
#pragma unroll
    for (int kn = 0; kn < 4; ++kn)
#pragma unroll
      for (int rp = 0; rp < 2; ++rp) {
        U32P pk;
        pk.h[0] = (bf16_t)p[kn][2 * rp];
        pk.h[1] = (bf16_t)p[kn][2 * rp + 1];
        *(unsigned*)&Pl[w][m16 * 72 + kn * 16 + quad * 4 + 2 * rp] = pk.u;
      }
    bf16x8 bp0 = *(const bf16x8*)&Pl[w][m16 * 72 + quad * 8];
    bf16x8 bp1 = *(const bf16x8*)&Pl[w][m16 * 72 + 32 + quad * 8];
#pragma unroll
    for (int ni = 0; ni < 4; ++ni) {
      bf16x8 av0 = *(const bf16x8*)&Vt[(ni * 16 + m16) * 72 + quad * 8];
      bf16x8 av1 = *(const bf16x8*)&Vt[(ni * 16 + m16) * 72 + 32 + quad * 8];
      acc[ni] = __builtin_amdgcn_mfma_f32_16x16x32_bf16(av0, bp0, acc[ni], 0, 0, 0);
      acc[ni] = __builtin_amdgcn_mfma_f32_16x16x32_bf16(av1, bp1, acc[ni], 0, 0, 0);
    }
  }

  // epilogue: lane holds O^T[dh = ni*16+quad*4+r][q = m16]
  float inv_l = 1.0f / l_run;
  bf16_t* cb = ctx + (size_t)(b * SS + qt * 64 + w * 16 + m16) * 1024 + h * 64;
#pragma unroll
  for (int ni = 0; ni < 4; ++ni)
#pragma unroll
    for (int rp = 0; rp < 2; ++rp) {
      U32P pk;
      pk.h[0] = (bf16_t)(acc[ni][2 * rp] * inv_l);
      pk.h[1] = (bf16_t)(acc[ni][2 * rp + 1] * inv_l);
      *(unsigned*)(cb + ni * 16 + quad * 4 + 2 * rp) = pk.u;
    }
}

// ---------------------------------------------------------------------------
extern "C" void kernel_launch(void* const* d_in, const int* in_sizes, int n_in,
                              void* d_out, int out_size, void* d_ws, size_t ws_size,
                              hipStream_t stream) {
  const float* hs    = (const float*)d_in[0];
  const float* alibi = (const float*)d_in[1];
  const float* qkvw  = (const float*)d_in[2];
  const float* qkvb  = (const float*)d_in[3];
  const float* dw    = (const float*)d_in[4];
  const float* db    = (const float*)d_in[5];
  const float* w1    = (const float*)d_in[6];
  const float* b1    = (const float*)d_in[7];
  const float* w2    = (const float*)d_in[8];
  const float* b2    = (const float*)d_in[9];
  const float* ln1w  = (const float*)d_in[10];
  const float* ln1b  = (const float*)d_in[11];
  const float* ln2w  = (const float*)d_in[12];
  const float* ln2b  = (const float*)d_in[13];
  float* x = (float*)d_out;  // residual stream, fp32 [4096,1024]

  char* ws = (char*)d_ws;
  bf16_t* wqc = (bf16_t*)(ws + 0);          // 2*3072*1024 bf16 = 12.6 MB
  bf16_t* wdc = (bf16_t*)(ws + 12582912);   // 2*1024*1024
  bf16_t* w1c = (bf16_t*)(ws + 16777216);   // 2*4096*1024
  bf16_t* w2c = (bf16_t*)(ws + 33554432);   // 2*1024*4096
  bf16_t* hb  = (bf16_t*)(ws + 50331648);   // 4096*1024 (ln out)
  bf16_t* qm  = (bf16_t*)(ws + 58720256);   // max(4096*3072, 4096*4096): qkv / mlp-mid aliased
  bf16_t* cx  = (bf16_t*)(ws + 92274688);   // 4096*1024 (attn ctx)

  hipMemcpyAsync(x, hs, (size_t)4096 * 1024 * 4, hipMemcpyDeviceToDevice, stream);
  cvt_kernel<<<6144, 256, 0, stream>>>(qkvw, wqc);
  cvt_kernel<<<2048, 256, 0, stream>>>(dw, wdc);
  cvt_kernel<<<8192, 256, 0, stream>>>(w1, w1c);
  cvt_kernel<<<8192, 256, 0, stream>>>(w2, w2c);

  for (int l = 0; l < 2; ++l) {
    ln_kernel<<<4096, 256, 0, stream>>>(x, ln1w + l * 1024, ln1b + l * 1024, hb);
    gemm_bt<0><<<dim3(24, 32), 256, 0, stream>>>(hb, wqc + (size_t)l * 3145728,
        qkvb + l * 3072, nullptr, qm, nullptr, 4096, 3072, 1024);
    attn_kernel<<<dim3(32, 32), 256, 0, stream>>>(qm, alibi, cx);
    gemm_bt<2><<<dim3(8, 32), 256, 0, stream>>>(cx, wdc + (size_t)l * 1048576,
        db + l * 1024, x, nullptr, x, 4096, 1024, 1024);
    ln_kernel<<<4096, 256, 0, stream>>>(x, ln2w + l * 1024, ln2b + l * 1024, hb);
    gemm_bt<1><<<dim3(32, 32), 256, 0, stream>>>(hb, w1c + (size_t)l * 4194304,
        b1 + l * 4096, nullptr, qm, nullptr, 4096, 4096, 1024);
    gemm_bt<2><<<dim3(8, 32), 256, 0, stream>>>(qm, w2c + (size_t)l * 4194304,
        b2 + l * 1024, x, nullptr, x, 4096, 1024, 4096);
  }
}